// Round 1
// baseline (343.411 us; speedup 1.0000x reference)
//
#include <hip/hip_runtime.h>
#include <math.h>

#define NB 32
#define NR 512
#define NT 128

// ---------------- wave (64-lane) reductions ----------------
__device__ __forceinline__ float wred_max(float v){
#pragma unroll
  for (int o = 32; o > 0; o >>= 1) v = fmaxf(v, __shfl_xor(v, o));
  return v;
}
__device__ __forceinline__ float wred_sum(float v){
#pragma unroll
  for (int o = 32; o > 0; o >>= 1) v += __shfl_xor(v, o);
  return v;
}

// ---------------- encoder kernel ----------------
// blocks 0..255: robots (64 robots/block); blocks 256..319: tasks (64 tasks/block)
// 256 threads: 4 threads per row (t4 = output quarter), 16 rows per wave.
// robot path: rf = relu(relu(rs@r_w1+b1)@r_w2+b2); then k = rf@wk+bk, v = rf@wv+bv,
//             rp = rf@a_w1[64:] (no bias)
// task path : tf0 = relu(relu(ts@t_w1+b1)@t_w2+b2); q = tf0@wq+bq
__global__ __launch_bounds__(256) void enc_kernel(
    const float* __restrict__ rs, const float* __restrict__ ts,
    const float* __restrict__ r_w1, const float* __restrict__ r_b1,
    const float* __restrict__ r_w2, const float* __restrict__ r_b2,
    const float* __restrict__ t_w1, const float* __restrict__ t_b1,
    const float* __restrict__ t_w2, const float* __restrict__ t_b2,
    const float* __restrict__ wq, const float* __restrict__ bq,
    const float* __restrict__ wk, const float* __restrict__ bk,
    const float* __restrict__ wv, const float* __restrict__ bv,
    const float* __restrict__ a_w1,
    float* __restrict__ kbuf, float* __restrict__ vbuf,
    float* __restrict__ rpbuf, float* __restrict__ qbuf)
{
  __shared__ float w1s[448];        // first-layer weights (7x64 or 6x64)
  __shared__ float wss[4096];       // 64x64 weight staging
  __shared__ float h_s[64 * 66];    // hidden, padded stride 66 (bank-friendly)
  __shared__ float rf_s[64 * 66];   // encoder output, padded

  const int tid = threadIdx.x;
  const int rb = tid >> 2, t4 = tid & 3;   // row-in-block, output quarter
  const int blk = blockIdx.x;
  const bool robot = blk < 256;

  if (robot) {
    if (tid < 112) ((float4*)w1s)[tid] = ((const float4*)r_w1)[tid];
#pragma unroll
    for (int c = 0; c < 4; ++c)
      ((float4*)wss)[c * 256 + tid] = ((const float4*)r_w2)[c * 256 + tid];
  } else {
    if (tid < 96) ((float4*)w1s)[tid] = ((const float4*)t_w1)[tid];
#pragma unroll
    for (int c = 0; c < 4; ++c)
      ((float4*)wss)[c * 256 + tid] = ((const float4*)t_w2)[c * 256 + tid];
  }

  int g, K1;
  const float* xin; const float* b1; const float* b2;
  if (robot) { g = blk * 64 + rb;        K1 = 7; xin = rs + (size_t)g * 7; b1 = r_b1; b2 = r_b2; }
  else       { g = (blk - 256) * 64 + rb; K1 = 6; xin = ts + (size_t)g * 6; b1 = t_b1; b2 = t_b2; }

  float x[7];
  for (int k = 0; k < K1; ++k) x[k] = xin[k];
  __syncthreads();

  // stage 1: hidden = relu(x @ W1 + b1)
  {
    float acc[16];
#pragma unroll
    for (int jj = 0; jj < 16; ++jj) acc[jj] = b1[t4 * 16 + jj];
    for (int k = 0; k < K1; ++k) {
      float xv = x[k];
#pragma unroll
      for (int jj = 0; jj < 16; ++jj) acc[jj] += xv * w1s[k * 64 + t4 * 16 + jj];
    }
#pragma unroll
    for (int jj = 0; jj < 16; ++jj) h_s[rb * 66 + t4 * 16 + jj] = fmaxf(acc[jj], 0.f);
  }
  __syncthreads();

  // stage 2: rf = relu(hidden @ W2 + b2)
  {
    float acc[16];
#pragma unroll
    for (int jj = 0; jj < 16; ++jj) acc[jj] = b2[t4 * 16 + jj];
    for (int k = 0; k < 64; ++k) {
      float hv = h_s[rb * 66 + k];
      const float4* wr = (const float4*)(wss + k * 64 + t4 * 16);
#pragma unroll
      for (int j4 = 0; j4 < 4; ++j4) {
        float4 w = wr[j4];
        acc[j4 * 4 + 0] += hv * w.x; acc[j4 * 4 + 1] += hv * w.y;
        acc[j4 * 4 + 2] += hv * w.z; acc[j4 * 4 + 3] += hv * w.w;
      }
    }
#pragma unroll
    for (int jj = 0; jj < 16; ++jj) rf_s[rb * 66 + t4 * 16 + jj] = fmaxf(acc[jj], 0.f);
  }

  // stage 3: projection passes
  const float* wp[3]; const float* bp[3]; float* op[3]; int npass;
  if (robot) {
    wp[0] = wk; bp[0] = bk;      op[0] = kbuf;
    wp[1] = wv; bp[1] = bv;      op[1] = vbuf;
    wp[2] = a_w1 + 64 * 64; bp[2] = nullptr; op[2] = rpbuf;
    npass = 3;
  } else {
    wp[0] = wq; bp[0] = bq; op[0] = qbuf; npass = 1;
  }
  for (int p = 0; p < npass; ++p) {
    __syncthreads();   // previous consumers of wss / writers of rf_s done
#pragma unroll
    for (int c = 0; c < 4; ++c)
      ((float4*)wss)[c * 256 + tid] = ((const float4*)wp[p])[c * 256 + tid];
    __syncthreads();
    float acc[16];
#pragma unroll
    for (int jj = 0; jj < 16; ++jj) acc[jj] = bp[p] ? bp[p][t4 * 16 + jj] : 0.f;
    for (int k = 0; k < 64; ++k) {
      float hv = rf_s[rb * 66 + k];
      const float4* wr = (const float4*)(wss + k * 64 + t4 * 16);
#pragma unroll
      for (int j4 = 0; j4 < 4; ++j4) {
        float4 w = wr[j4];
        acc[j4 * 4 + 0] += hv * w.x; acc[j4 * 4 + 1] += hv * w.y;
        acc[j4 * 4 + 2] += hv * w.z; acc[j4 * 4 + 3] += hv * w.w;
      }
    }
    float4* o4 = (float4*)(op[p] + (size_t)g * 64 + t4 * 16);
#pragma unroll
    for (int j4 = 0; j4 < 4; ++j4)
      o4[j4] = make_float4(acc[j4 * 4 + 0], acc[j4 * 4 + 1], acc[j4 * 4 + 2], acc[j4 * 4 + 3]);
  }
}

// ---------------- attention kernel ----------------
// 1024 blocks x 256 threads; each block: one batch b, 4 consecutive tasks.
// XCD swizzle: blocks with the same b land on the same XCD (b = f(blk%32)).
// Computes logits (q.k/4), per-head softmax, ctx = p.v, tf = ctx@wo+bo,
// tp = tf@a_w1[:64] + a_b1  -> tpbuf
__global__ __launch_bounds__(256) void attn_kernel(
    const float* __restrict__ qbuf, const float* __restrict__ kbuf,
    const float* __restrict__ vbuf,
    const float* __restrict__ wo, const float* __restrict__ bo,
    const float* __restrict__ a_w1, const float* __restrict__ a_b1,
    float* __restrict__ tpbuf)
{
  __shared__ float qs[4 * 64];          // scaled q, 4 tasks
  __shared__ float lg[4][4 * 512];      // [task][head*512 + r] logits -> exp(p)
  __shared__ float inv_s[16];           // [task*4+head] 1/sum
  __shared__ float cp[4][4 * 64];       // partials [chunk][task*64 + od]
  __shared__ float ctx_s[4 * 64];
  __shared__ float tf_s[4 * 64];

  const int tid = threadIdx.x;
  const int jj = blockIdx.x & 31;
  const int b  = (jj & 7) * 4 + (jj >> 3);
  const int t0 = (blockIdx.x >> 5) * 4;

  if (tid < 64) {
    int tt = tid >> 4, i4 = tid & 15;
    float4 v = ((const float4*)(qbuf + (size_t)(b * NT + t0 + tt) * 64))[i4];
    v.x *= 0.25f; v.y *= 0.25f; v.z *= 0.25f; v.w *= 0.25f;   // 1/sqrt(16)
    ((float4*)qs)[tid] = v;
  }
  __syncthreads();

  // phase A: logits
  for (int rr = 0; rr < 2; ++rr) {
    int r = rr * 256 + tid;
    const float4* k4 = (const float4*)(kbuf + (size_t)(b * NR + r) * 64);
    float4 kk[16];
#pragma unroll
    for (int i = 0; i < 16; ++i) kk[i] = k4[i];
#pragma unroll
    for (int tt = 0; tt < 4; ++tt) {
      const float4* q4 = (const float4*)(qs + tt * 64);
#pragma unroll
      for (int h = 0; h < 4; ++h) {
        float s = 0.f;
#pragma unroll
        for (int i = 0; i < 4; ++i) {
          float4 qv = q4[h * 4 + i], kv = kk[h * 4 + i];
          s += qv.x * kv.x + qv.y * kv.y + qv.z * kv.z + qv.w * kv.w;
        }
        lg[tt][h * 512 + r] = s;
      }
    }
  }
  __syncthreads();

  // phase B: per-(task,head) softmax (un-normalized exp + inv sum); wave = task
  {
    int wid = tid >> 6, lane = tid & 63;
    for (int h = 0; h < 4; ++h) {
      float* row = &lg[wid][h * 512];
      float v0[8];
#pragma unroll
      for (int u = 0; u < 8; ++u) v0[u] = row[u * 64 + lane];
      float m = v0[0];
#pragma unroll
      for (int u = 1; u < 8; ++u) m = fmaxf(m, v0[u]);
      m = wred_max(m);
      float s = 0.f;
#pragma unroll
      for (int u = 0; u < 8; ++u) {
        float e = expf(v0[u] - m);
        row[u * 64 + lane] = e;
        s += e;
      }
      s = wred_sum(s);
      if (lane == 0) inv_s[wid * 4 + h] = 1.f / s;
    }
  }
  __syncthreads();

  // phase C: ctx[tt][h*16+d] = sum_r p * v   (r chunked over 4 waves)
  {
    int od = tid & 63, ch = tid >> 6;
    int h = od >> 4, d = od & 15;
    float acc[4] = {0.f, 0.f, 0.f, 0.f};
    const float* vptr = vbuf + (size_t)b * NR * 64 + h * 16 + d;
    for (int u = 0; u < 128; ++u) {
      int r = ch * 128 + u;
      float vv = vptr[(size_t)r * 64];
#pragma unroll
      for (int tt = 0; tt < 4; ++tt) acc[tt] += lg[tt][h * 512 + r] * vv;
    }
#pragma unroll
    for (int tt = 0; tt < 4; ++tt) cp[ch][tt * 64 + od] = acc[tt];
  }
  __syncthreads();
  {
    int tt = tid >> 6, od = tid & 63, h = od >> 4;
    ctx_s[tt * 64 + od] =
        (cp[0][tt * 64 + od] + cp[1][tt * 64 + od] +
         cp[2][tt * 64 + od] + cp[3][tt * 64 + od]) * inv_s[tt * 4 + h];
  }
  __syncthreads();

  // phase D: tf = ctx @ wo + bo
  {
    int jd = tid & 63, kc = tid >> 6;
    float p[4] = {0.f, 0.f, 0.f, 0.f};
    for (int k = 0; k < 16; ++k) {
      float w = wo[(kc * 16 + k) * 64 + jd];
#pragma unroll
      for (int tt = 0; tt < 4; ++tt) p[tt] += ctx_s[tt * 64 + kc * 16 + k] * w;
    }
#pragma unroll
    for (int tt = 0; tt < 4; ++tt) cp[kc][tt * 64 + jd] = p[tt];
  }
  __syncthreads();
  {
    int tt = tid >> 6, jd = tid & 63;
    tf_s[tt * 64 + jd] = cp[0][tt * 64 + jd] + cp[1][tt * 64 + jd] +
                         cp[2][tt * 64 + jd] + cp[3][tt * 64 + jd] + bo[jd];
  }
  __syncthreads();

  // tp = tf @ a_w1[:64] + a_b1  (a_b1 folded here so pair kernel skips it)
  {
    int jd = tid & 63, kc = tid >> 6;
    float p[4] = {0.f, 0.f, 0.f, 0.f};
    for (int k = 0; k < 16; ++k) {
      float w = a_w1[(kc * 16 + k) * 64 + jd];
#pragma unroll
      for (int tt = 0; tt < 4; ++tt) p[tt] += tf_s[tt * 64 + kc * 16 + k] * w;
    }
#pragma unroll
    for (int tt = 0; tt < 4; ++tt) cp[kc][tt * 64 + jd] = p[tt];
  }
  __syncthreads();
  {
    int tt = tid >> 6, jd = tid & 63;
    tpbuf[(size_t)(b * NT + t0 + tt) * 64 + jd] =
        cp[0][tt * 64 + jd] + cp[1][tt * 64 + jd] +
        cp[2][tt * 64 + jd] + cp[3][tt * 64 + jd] + a_b1[jd];
  }
}

// ---------------- pairwise allocation kernel ----------------
// 4096 blocks (one per (b,t)), 256 threads, 2 robots/thread.
// h1 = relu(tp + rp); h2 = relu(h1@W2 + b2); score = h2.w3 + b3; softmax over r.
__global__ __launch_bounds__(256) void pair_kernel(
    const float* __restrict__ tpbuf, const float* __restrict__ rpbuf,
    const float* __restrict__ a_w2, const float* __restrict__ a_b2,
    const float* __restrict__ a_w3, const float* __restrict__ a_b3,
    float* __restrict__ out)
{
  __shared__ float tp_s[64];
  __shared__ float w2_s[2048];
  __shared__ float b2_s[32];
  __shared__ float w3_s[32];
  __shared__ float red_a[4];
  __shared__ float red_b[4];

  const int tid = threadIdx.x;
  const int jj = blockIdx.x & 31;
  const int b  = (jj & 7) * 4 + (jj >> 3);   // XCD-locality swizzle (same as attn)
  const int t  = blockIdx.x >> 5;

  if (tid < 16)
    ((float4*)tp_s)[tid] = ((const float4*)(tpbuf + (size_t)(b * NT + t) * 64))[tid];
  ((float4*)w2_s)[tid]       = ((const float4*)a_w2)[tid];
  ((float4*)w2_s)[256 + tid] = ((const float4*)a_w2)[256 + tid];
  if (tid < 8)                ((float4*)b2_s)[tid]     = ((const float4*)a_b2)[tid];
  if (tid >= 8 && tid < 16)   ((float4*)w3_s)[tid - 8] = ((const float4*)a_w3)[tid - 8];
  __syncthreads();

  const float b3 = a_b3[0];
  const float* rpb = rpbuf + (size_t)b * NR * 64;
  float sc[2];

  for (int rr = 0; rr < 2; ++rr) {
    int r = rr * 256 + tid;
    const float4* rp4 = (const float4*)(rpb + (size_t)r * 64);
    float acc[32];
#pragma unroll
    for (int q = 0; q < 32; ++q) acc[q] = b2_s[q];
#pragma unroll 4
    for (int i4 = 0; i4 < 16; ++i4) {
      float4 rv = rp4[i4];
      float4 tv = ((const float4*)tp_s)[i4];
      float h[4];
      h[0] = fmaxf(rv.x + tv.x, 0.f);
      h[1] = fmaxf(rv.y + tv.y, 0.f);
      h[2] = fmaxf(rv.z + tv.z, 0.f);
      h[3] = fmaxf(rv.w + tv.w, 0.f);
#pragma unroll
      for (int u = 0; u < 4; ++u) {
        const float4* wr = (const float4*)(w2_s + (i4 * 4 + u) * 32);
        float hv = h[u];
#pragma unroll
        for (int j4 = 0; j4 < 8; ++j4) {
          float4 w = wr[j4];
          acc[j4 * 4 + 0] += hv * w.x; acc[j4 * 4 + 1] += hv * w.y;
          acc[j4 * 4 + 2] += hv * w.z; acc[j4 * 4 + 3] += hv * w.w;
        }
      }
    }
    float s = b3;
#pragma unroll
    for (int q = 0; q < 32; ++q) s += fmaxf(acc[q], 0.f) * w3_s[q];
    sc[rr] = s;
  }

  // block softmax over 512 scores (2 per thread)
  int lane = tid & 63, wid = tid >> 6;
  float mw = wred_max(fmaxf(sc[0], sc[1]));
  if (lane == 0) red_a[wid] = mw;
  __syncthreads();
  float m = fmaxf(fmaxf(red_a[0], red_a[1]), fmaxf(red_a[2], red_a[3]));
  float e0 = expf(sc[0] - m), e1 = expf(sc[1] - m);
  float sw = wred_sum(e0 + e1);
  if (lane == 0) red_b[wid] = sw;
  __syncthreads();
  float inv = 1.f / (red_b[0] + red_b[1] + red_b[2] + red_b[3]);

  float* op = out + (size_t)(b * NT + t) * NR;
  op[tid]       = e0 * inv;
  op[256 + tid] = e1 * inv;
}

// ---------------- launch ----------------
extern "C" void kernel_launch(void* const* d_in, const int* in_sizes, int n_in,
                              void* d_out, int out_size, void* d_ws, size_t ws_size,
                              hipStream_t stream)
{
  const float* rs   = (const float*)d_in[0];
  const float* ts   = (const float*)d_in[1];
  const float* r_w1 = (const float*)d_in[2];  const float* r_b1 = (const float*)d_in[3];
  const float* r_w2 = (const float*)d_in[4];  const float* r_b2 = (const float*)d_in[5];
  const float* t_w1 = (const float*)d_in[6];  const float* t_b1 = (const float*)d_in[7];
  const float* t_w2 = (const float*)d_in[8];  const float* t_b2 = (const float*)d_in[9];
  const float* wq   = (const float*)d_in[10]; const float* bq   = (const float*)d_in[11];
  const float* wk   = (const float*)d_in[12]; const float* bk   = (const float*)d_in[13];
  const float* wv   = (const float*)d_in[14]; const float* bv   = (const float*)d_in[15];
  const float* wo   = (const float*)d_in[16]; const float* bo   = (const float*)d_in[17];
  const float* a_w1 = (const float*)d_in[18]; const float* a_b1 = (const float*)d_in[19];
  const float* a_w2 = (const float*)d_in[20]; const float* a_b2 = (const float*)d_in[21];
  const float* a_w3 = (const float*)d_in[22]; const float* a_b3 = (const float*)d_in[23];

  float* wsf   = (float*)d_ws;
  float* kbuf  = wsf;                                   // 32*512*64
  float* vbuf  = kbuf  + (size_t)NB * NR * 64;          // 32*512*64
  float* rpbuf = vbuf  + (size_t)NB * NR * 64;          // 32*512*64
  float* qbuf  = rpbuf + (size_t)NB * NR * 64;          // 32*128*64
  float* tpbuf = qbuf  + (size_t)NB * NT * 64;          // 32*128*64

  enc_kernel<<<dim3(320), dim3(256), 0, stream>>>(
      rs, ts, r_w1, r_b1, r_w2, r_b2, t_w1, t_b1, t_w2, t_b2,
      wq, bq, wk, bk, wv, bv, a_w1, kbuf, vbuf, rpbuf, qbuf);

  attn_kernel<<<dim3(1024), dim3(256), 0, stream>>>(
      qbuf, kbuf, vbuf, wo, bo, a_w1, a_b1, tpbuf);

  pair_kernel<<<dim3(4096), dim3(256), 0, stream>>>(
      tpbuf, rpbuf, a_w2, a_b2, a_w3, a_b3, (float*)d_out);
}

// Round 2
// 293.575 us; speedup vs baseline: 1.1698x; 1.1698x over previous
//
#include <hip/hip_runtime.h>
#include <math.h>

#define NB 32
#define NR 512
#define NT 128

// ---------------- wave (64-lane) reductions ----------------
__device__ __forceinline__ float wred_max(float v){
#pragma unroll
  for (int o = 32; o > 0; o >>= 1) v = fmaxf(v, __shfl_xor(v, o));
  return v;
}
__device__ __forceinline__ float wred_sum(float v){
#pragma unroll
  for (int o = 32; o > 0; o >>= 1) v += __shfl_xor(v, o);
  return v;
}

// ---------------- encoder kernel ----------------
// blocks 0..255: robots (64 robots/block); blocks 256..319: tasks (64 tasks/block)
__global__ __launch_bounds__(256) void enc_kernel(
    const float* __restrict__ rs, const float* __restrict__ ts,
    const float* __restrict__ r_w1, const float* __restrict__ r_b1,
    const float* __restrict__ r_w2, const float* __restrict__ r_b2,
    const float* __restrict__ t_w1, const float* __restrict__ t_b1,
    const float* __restrict__ t_w2, const float* __restrict__ t_b2,
    const float* __restrict__ wq, const float* __restrict__ bq,
    const float* __restrict__ wk, const float* __restrict__ bk,
    const float* __restrict__ wv, const float* __restrict__ bv,
    const float* __restrict__ a_w1,
    float* __restrict__ kbuf, float* __restrict__ vbuf,
    float* __restrict__ rpbuf, float* __restrict__ qbuf)
{
  __shared__ float w1s[448];        // first-layer weights (7x64 or 6x64)
  __shared__ float wss[4096];       // 64x64 weight staging
  __shared__ float h_s[64 * 66];    // hidden, padded stride 66
  __shared__ float rf_s[64 * 66];   // encoder output, padded

  const int tid = threadIdx.x;
  const int rb = tid >> 2, t4 = tid & 3;   // row-in-block, output quarter
  const int blk = blockIdx.x;
  const bool robot = blk < 256;

  if (robot) {
    if (tid < 112) ((float4*)w1s)[tid] = ((const float4*)r_w1)[tid];
#pragma unroll
    for (int c = 0; c < 4; ++c)
      ((float4*)wss)[c * 256 + tid] = ((const float4*)r_w2)[c * 256 + tid];
  } else {
    if (tid < 96) ((float4*)w1s)[tid] = ((const float4*)t_w1)[tid];
#pragma unroll
    for (int c = 0; c < 4; ++c)
      ((float4*)wss)[c * 256 + tid] = ((const float4*)t_w2)[c * 256 + tid];
  }

  int g, K1;
  const float* xin; const float* b1; const float* b2;
  if (robot) { g = blk * 64 + rb;        K1 = 7; xin = rs + (size_t)g * 7; b1 = r_b1; b2 = r_b2; }
  else       { g = (blk - 256) * 64 + rb; K1 = 6; xin = ts + (size_t)g * 6; b1 = t_b1; b2 = t_b2; }

  float x[7];
  for (int k = 0; k < K1; ++k) x[k] = xin[k];
  __syncthreads();

  // stage 1: hidden = relu(x @ W1 + b1)
  {
    float acc[16];
#pragma unroll
    for (int jj = 0; jj < 16; ++jj) acc[jj] = b1[t4 * 16 + jj];
    for (int k = 0; k < K1; ++k) {
      float xv = x[k];
#pragma unroll
      for (int jj = 0; jj < 16; ++jj) acc[jj] += xv * w1s[k * 64 + t4 * 16 + jj];
    }
#pragma unroll
    for (int jj = 0; jj < 16; ++jj) h_s[rb * 66 + t4 * 16 + jj] = fmaxf(acc[jj], 0.f);
  }
  __syncthreads();

  // stage 2: rf = relu(hidden @ W2 + b2)
  {
    float acc[16];
#pragma unroll
    for (int jj = 0; jj < 16; ++jj) acc[jj] = b2[t4 * 16 + jj];
    for (int k = 0; k < 64; ++k) {
      float hv = h_s[rb * 66 + k];
      const float4* wr = (const float4*)(wss + k * 64 + t4 * 16);
#pragma unroll
      for (int j4 = 0; j4 < 4; ++j4) {
        float4 w = wr[j4];
        acc[j4 * 4 + 0] += hv * w.x; acc[j4 * 4 + 1] += hv * w.y;
        acc[j4 * 4 + 2] += hv * w.z; acc[j4 * 4 + 3] += hv * w.w;
      }
    }
#pragma unroll
    for (int jj = 0; jj < 16; ++jj) rf_s[rb * 66 + t4 * 16 + jj] = fmaxf(acc[jj], 0.f);
  }

  // stage 3: projection passes
  const float* wp[3]; const float* bp[3]; float* op[3]; int npass;
  if (robot) {
    wp[0] = wk; bp[0] = bk;      op[0] = kbuf;
    wp[1] = wv; bp[1] = bv;      op[1] = vbuf;
    wp[2] = a_w1 + 64 * 64; bp[2] = nullptr; op[2] = rpbuf;
    npass = 3;
  } else {
    wp[0] = wq; bp[0] = bq; op[0] = qbuf; npass = 1;
  }
  for (int p = 0; p < npass; ++p) {
    __syncthreads();
#pragma unroll
    for (int c = 0; c < 4; ++c)
      ((float4*)wss)[c * 256 + tid] = ((const float4*)wp[p])[c * 256 + tid];
    __syncthreads();
    float acc[16];
#pragma unroll
    for (int jj = 0; jj < 16; ++jj) acc[jj] = bp[p] ? bp[p][t4 * 16 + jj] : 0.f;
    for (int k = 0; k < 64; ++k) {
      float hv = rf_s[rb * 66 + k];
      const float4* wr = (const float4*)(wss + k * 64 + t4 * 16);
#pragma unroll
      for (int j4 = 0; j4 < 4; ++j4) {
        float4 w = wr[j4];
        acc[j4 * 4 + 0] += hv * w.x; acc[j4 * 4 + 1] += hv * w.y;
        acc[j4 * 4 + 2] += hv * w.z; acc[j4 * 4 + 3] += hv * w.w;
      }
    }
    float4* o4 = (float4*)(op[p] + (size_t)g * 64 + t4 * 16);
#pragma unroll
    for (int j4 = 0; j4 < 4; ++j4)
      o4[j4] = make_float4(acc[j4 * 4 + 0], acc[j4 * 4 + 1], acc[j4 * 4 + 2], acc[j4 * 4 + 3]);
  }
}

// ---------------- attention kernel ----------------
__global__ __launch_bounds__(256) void attn_kernel(
    const float* __restrict__ qbuf, const float* __restrict__ kbuf,
    const float* __restrict__ vbuf,
    const float* __restrict__ wo, const float* __restrict__ bo,
    const float* __restrict__ a_w1, const float* __restrict__ a_b1,
    float* __restrict__ tpbuf)
{
  __shared__ float qs[4 * 64];          // scaled q, 4 tasks
  __shared__ float lg[4][4 * 512];      // [task][head*512 + r] logits -> exp(p)
  __shared__ float inv_s[16];           // [task*4+head] 1/sum
  __shared__ float cp[4][4 * 64];       // partials [chunk][task*64 + od]
  __shared__ float ctx_s[4 * 64];
  __shared__ float tf_s[4 * 64];

  const int tid = threadIdx.x;
  const int jj = blockIdx.x & 31;
  const int b  = (jj & 7) * 4 + (jj >> 3);
  const int t0 = (blockIdx.x >> 5) * 4;

  if (tid < 64) {
    int tt = tid >> 4, i4 = tid & 15;
    float4 v = ((const float4*)(qbuf + (size_t)(b * NT + t0 + tt) * 64))[i4];
    v.x *= 0.25f; v.y *= 0.25f; v.z *= 0.25f; v.w *= 0.25f;   // 1/sqrt(16)
    ((float4*)qs)[tid] = v;
  }
  __syncthreads();

  // phase A: logits
  for (int rr = 0; rr < 2; ++rr) {
    int r = rr * 256 + tid;
    const float4* k4 = (const float4*)(kbuf + (size_t)(b * NR + r) * 64);
    float4 kk[16];
#pragma unroll
    for (int i = 0; i < 16; ++i) kk[i] = k4[i];
#pragma unroll
    for (int tt = 0; tt < 4; ++tt) {
      const float4* q4 = (const float4*)(qs + tt * 64);
#pragma unroll
      for (int h = 0; h < 4; ++h) {
        float s = 0.f;
#pragma unroll
        for (int i = 0; i < 4; ++i) {
          float4 qv = q4[h * 4 + i], kv = kk[h * 4 + i];
          s += qv.x * kv.x + qv.y * kv.y + qv.z * kv.z + qv.w * kv.w;
        }
        lg[tt][h * 512 + r] = s;
      }
    }
  }
  __syncthreads();

  // phase B: per-(task,head) softmax
  {
    int wid = tid >> 6, lane = tid & 63;
    for (int h = 0; h < 4; ++h) {
      float* row = &lg[wid][h * 512];
      float v0[8];
#pragma unroll
      for (int u = 0; u < 8; ++u) v0[u] = row[u * 64 + lane];
      float m = v0[0];
#pragma unroll
      for (int u = 1; u < 8; ++u) m = fmaxf(m, v0[u]);
      m = wred_max(m);
      float s = 0.f;
#pragma unroll
      for (int u = 0; u < 8; ++u) {
        float e = expf(v0[u] - m);
        row[u * 64 + lane] = e;
        s += e;
      }
      s = wred_sum(s);
      if (lane == 0) inv_s[wid * 4 + h] = 1.f / s;
    }
  }
  __syncthreads();

  // phase C: ctx = p.v
  {
    int od = tid & 63, ch = tid >> 6;
    int h = od >> 4, d = od & 15;
    float acc[4] = {0.f, 0.f, 0.f, 0.f};
    const float* vptr = vbuf + (size_t)b * NR * 64 + h * 16 + d;
    for (int u = 0; u < 128; ++u) {
      int r = ch * 128 + u;
      float vv = vptr[(size_t)r * 64];
#pragma unroll
      for (int tt = 0; tt < 4; ++tt) acc[tt] += lg[tt][h * 512 + r] * vv;
    }
#pragma unroll
    for (int tt = 0; tt < 4; ++tt) cp[ch][tt * 64 + od] = acc[tt];
  }
  __syncthreads();
  {
    int tt = tid >> 6, od = tid & 63, h = od >> 4;
    ctx_s[tt * 64 + od] =
        (cp[0][tt * 64 + od] + cp[1][tt * 64 + od] +
         cp[2][tt * 64 + od] + cp[3][tt * 64 + od]) * inv_s[tt * 4 + h];
  }
  __syncthreads();

  // phase D: tf = ctx @ wo + bo
  {
    int jd = tid & 63, kc = tid >> 6;
    float p[4] = {0.f, 0.f, 0.f, 0.f};
    for (int k = 0; k < 16; ++k) {
      float w = wo[(kc * 16 + k) * 64 + jd];
#pragma unroll
      for (int tt = 0; tt < 4; ++tt) p[tt] += ctx_s[tt * 64 + kc * 16 + k] * w;
    }
#pragma unroll
    for (int tt = 0; tt < 4; ++tt) cp[kc][tt * 64 + jd] = p[tt];
  }
  __syncthreads();
  {
    int tt = tid >> 6, jd = tid & 63;
    tf_s[tt * 64 + jd] = cp[0][tt * 64 + jd] + cp[1][tt * 64 + jd] +
                         cp[2][tt * 64 + jd] + cp[3][tt * 64 + jd] + bo[jd];
  }
  __syncthreads();

  // tp = tf @ a_w1[:64] + a_b1
  {
    int jd = tid & 63, kc = tid >> 6;
    float p[4] = {0.f, 0.f, 0.f, 0.f};
    for (int k = 0; k < 16; ++k) {
      float w = a_w1[(kc * 16 + k) * 64 + jd];
#pragma unroll
      for (int tt = 0; tt < 4; ++tt) p[tt] += tf_s[tt * 64 + kc * 16 + k] * w;
    }
#pragma unroll
    for (int tt = 0; tt < 4; ++tt) cp[kc][tt * 64 + jd] = p[tt];
  }
  __syncthreads();
  {
    int tt = tid >> 6, jd = tid & 63;
    tpbuf[(size_t)(b * NT + t0 + tt) * 64 + jd] =
        cp[0][tt * 64 + jd] + cp[1][tt * 64 + jd] +
        cp[2][tt * 64 + jd] + cp[3][tt * 64 + jd] + a_b1[jd];
  }
}

// ---------------- pairwise allocation kernel (v2: SGPR-resident weights) ----
// 4096 blocks (one per (b,t)), 256 threads, 2 robots/thread.
// ALL uniform operands (tp row, W2, b2, w3, b3) are read via wave-uniform
// global addresses -> compiler scalarizes to s_load (scalar cache), so the
// inner loop is pure v_fmac_f32 with one SGPR operand. No LDS broadcast.
__global__ __launch_bounds__(256) void pair_kernel(
    const float* __restrict__ tpbuf, const float* __restrict__ rpbuf,
    const float* __restrict__ a_w2, const float* __restrict__ a_b2,
    const float* __restrict__ a_w3, const float* __restrict__ a_b3,
    float* __restrict__ out)
{
  __shared__ float red_a[4];
  __shared__ float red_b[4];

  const int tid = threadIdx.x;
  const int jj = blockIdx.x & 31;
  const int b  = (jj & 7) * 4 + (jj >> 3);   // XCD-locality swizzle
  const int t  = blockIdx.x >> 5;

  const float* tp  = tpbuf + (size_t)(b * NT + t) * 64;          // uniform
  const float* rp0 = rpbuf + ((size_t)b * NR + tid) * 64;        // robot tid
  const float* rp1 = rp0 + 256 * 64;                             // robot tid+256

  float acc0[32], acc1[32];
#pragma unroll
  for (int q = 0; q < 32; ++q) { float bb = a_b2[q]; acc0[q] = bb; acc1[q] = bb; }

#pragma unroll 4
  for (int k4 = 0; k4 < 16; ++k4) {
    float4 r0 = ((const float4*)rp0)[k4];
    float4 r1 = ((const float4*)rp1)[k4];
    float4 tv = ((const float4*)tp)[k4];     // uniform -> s_load_dwordx4
    float h0[4], h1[4];
    h0[0] = fmaxf(r0.x + tv.x, 0.f); h1[0] = fmaxf(r1.x + tv.x, 0.f);
    h0[1] = fmaxf(r0.y + tv.y, 0.f); h1[1] = fmaxf(r1.y + tv.y, 0.f);
    h0[2] = fmaxf(r0.z + tv.z, 0.f); h1[2] = fmaxf(r1.z + tv.z, 0.f);
    h0[3] = fmaxf(r0.w + tv.w, 0.f); h1[3] = fmaxf(r1.w + tv.w, 0.f);
#pragma unroll
    for (int u = 0; u < 4; ++u) {
      const float* wr = a_w2 + (k4 * 4 + u) * 32;  // uniform row
      float a = h0[u], c = h1[u];
#pragma unroll
      for (int q = 0; q < 32; ++q) {
        float w = wr[q];                     // uniform -> s_load
        acc0[q] += a * w;
        acc1[q] += c * w;
      }
    }
  }

  float s0 = a_b3[0], s1 = s0;
#pragma unroll
  for (int q = 0; q < 32; ++q) {
    float w3 = a_w3[q];                      // uniform -> s_load
    s0 += fmaxf(acc0[q], 0.f) * w3;
    s1 += fmaxf(acc1[q], 0.f) * w3;
  }

  // block softmax over 512 scores (2 per thread)
  int lane = tid & 63, wid = tid >> 6;
  float mw = wred_max(fmaxf(s0, s1));
  if (lane == 0) red_a[wid] = mw;
  __syncthreads();
  float m = fmaxf(fmaxf(red_a[0], red_a[1]), fmaxf(red_a[2], red_a[3]));
  float e0 = expf(s0 - m), e1 = expf(s1 - m);
  float sw = wred_sum(e0 + e1);
  if (lane == 0) red_b[wid] = sw;
  __syncthreads();
  float inv = 1.f / (red_b[0] + red_b[1] + red_b[2] + red_b[3]);

  float* op = out + (size_t)(b * NT + t) * NR;
  op[tid]       = e0 * inv;
  op[256 + tid] = e1 * inv;
}

// ---------------- launch ----------------
extern "C" void kernel_launch(void* const* d_in, const int* in_sizes, int n_in,
                              void* d_out, int out_size, void* d_ws, size_t ws_size,
                              hipStream_t stream)
{
  const float* rs   = (const float*)d_in[0];
  const float* ts   = (const float*)d_in[1];
  const float* r_w1 = (const float*)d_in[2];  const float* r_b1 = (const float*)d_in[3];
  const float* r_w2 = (const float*)d_in[4];  const float* r_b2 = (const float*)d_in[5];
  const float* t_w1 = (const float*)d_in[6];  const float* t_b1 = (const float*)d_in[7];
  const float* t_w2 = (const float*)d_in[8];  const float* t_b2 = (const float*)d_in[9];
  const float* wq   = (const float*)d_in[10]; const float* bq   = (const float*)d_in[11];
  const float* wk   = (const float*)d_in[12]; const float* bk   = (const float*)d_in[13];
  const float* wv   = (const float*)d_in[14]; const float* bv   = (const float*)d_in[15];
  const float* wo   = (const float*)d_in[16]; const float* bo   = (const float*)d_in[17];
  const float* a_w1 = (const float*)d_in[18]; const float* a_b1 = (const float*)d_in[19];
  const float* a_w2 = (const float*)d_in[20]; const float* a_b2 = (const float*)d_in[21];
  const float* a_w3 = (const float*)d_in[22]; const float* a_b3 = (const float*)d_in[23];

  float* wsf   = (float*)d_ws;
  float* kbuf  = wsf;                                   // 32*512*64
  float* vbuf  = kbuf  + (size_t)NB * NR * 64;          // 32*512*64
  float* rpbuf = vbuf  + (size_t)NB * NR * 64;          // 32*512*64
  float* qbuf  = rpbuf + (size_t)NB * NR * 64;          // 32*128*64
  float* tpbuf = qbuf  + (size_t)NB * NT * 64;          // 32*128*64

  enc_kernel<<<dim3(320), dim3(256), 0, stream>>>(
      rs, ts, r_w1, r_b1, r_w2, r_b2, t_w1, t_b1, t_w2, t_b2,
      wq, bq, wk, bk, wv, bv, a_w1, kbuf, vbuf, rpbuf, qbuf);

  attn_kernel<<<dim3(1024), dim3(256), 0, stream>>>(
      qbuf, kbuf, vbuf, wo, bo, a_w1, a_b1, tpbuf);

  pair_kernel<<<dim3(4096), dim3(256), 0, stream>>>(
      tpbuf, rpbuf, a_w2, a_b2, a_w3, a_b3, (float*)d_out);
}